// Round 11
// baseline (143.844 us; speedup 1.0000x reference)
//
#include <hip/hip_runtime.h>
#include <hip/hip_fp16.h>

// NCC loss: 9^3 box sums of {I, J, I*I, J*J, I*J}, per-voxel cc, -mean(cc).
// Dims: C=2, D=192, H=224, W=192, fp32. Full-volume two-pass:
//   K1 (k_hwsum): ZERO-LDS / ZERO-CROSS-LANE. Thread owns 4 output px and
//     redundantly loads its full 12-px W-span (3 overlapping float4 of I and
//     J per row; overlap served by L1/L2). H running sums via add row h+4 /
//     re-load row h-4 (cache-hot) — no ring, no LDS, no shuffles, no
//     barriers. Targets the LDS-pipe saturation (~180-360 LDS-cyc/step ≈
//     65-100% of duration) common to all ten prior K1 variants.
//   K2 (k_dsum): D-sum — barrier-free streaming register ring + cc + reduce.

#define C2   2
#define DDIM 192
#define HDIM 224
#define WDIM 192
#define HWN  (HDIM*WDIM)              // 43008
#define VOL  ((size_t)DDIM*HWN)       // 8257536
#define RAD  4
#define WINV (1.0f/729.0f)

#define HT1  28   // h-strip (224/28 = 8 strips); 2400 waves, fully resident

__device__ __forceinline__ float4 zero4() { float4 z; z.x=z.y=z.z=z.w=0.f; return z; }

__device__ __forceinline__ void padd(float4& r0, float4& r1, float4& r2,
                                     float4& r3, float4& r4,
                                     const float4 a, const float4 b) {
    r0.x+=a.x; r0.y+=a.y; r0.z+=a.z; r0.w+=a.w;
    r1.x+=b.x; r1.y+=b.y; r1.z+=b.z; r1.w+=b.w;
    r2.x=fmaf(a.x,a.x,r2.x); r2.y=fmaf(a.y,a.y,r2.y);
    r2.z=fmaf(a.z,a.z,r2.z); r2.w=fmaf(a.w,a.w,r2.w);
    r3.x=fmaf(b.x,b.x,r3.x); r3.y=fmaf(b.y,b.y,r3.y);
    r3.z=fmaf(b.z,b.z,r3.z); r3.w=fmaf(b.w,b.w,r3.w);
    r4.x=fmaf(a.x,b.x,r4.x); r4.y=fmaf(a.y,b.y,r4.y);
    r4.z=fmaf(a.z,b.z,r4.z); r4.w=fmaf(a.w,b.w,r4.w);
}
__device__ __forceinline__ void psub(float4& r0, float4& r1, float4& r2,
                                     float4& r3, float4& r4,
                                     const float4 a, const float4 b) {
    r0.x-=a.x; r0.y-=a.y; r0.z-=a.z; r0.w-=a.w;
    r1.x-=b.x; r1.y-=b.y; r1.z-=b.z; r1.w-=b.w;
    r2.x=fmaf(-a.x,a.x,r2.x); r2.y=fmaf(-a.y,a.y,r2.y);
    r2.z=fmaf(-a.z,a.z,r2.z); r2.w=fmaf(-a.w,a.w,r2.w);
    r3.x=fmaf(-b.x,b.x,r3.x); r3.y=fmaf(-b.y,b.y,r3.y);
    r3.z=fmaf(-b.z,b.z,r3.z); r3.w=fmaf(-b.w,b.w,r3.w);
    r4.x=fmaf(-a.x,b.x,r4.x); r4.y=fmaf(-a.y,b.y,r4.y);
    r4.z=fmaf(-a.z,b.z,r4.z); r4.w=fmaf(-a.w,b.w,r4.w);
}

// ---------------- K1: H-sum + W-sum of 5 product fields, zero-LDS ----------------
// grid: ((nd+3)/4, HDIM/HT1, C2); block: 192 = 48 w-groups x 4 d-slices
// buf layout (fp16): [f][c][bd][h][w], bd = d - d0 + 4, fstride = C2*bufD*HWN
__global__ __launch_bounds__(192)
void k_hwsum(const float* __restrict__ I, const float* __restrict__ J,
             __half* __restrict__ buf, int d0, int dbeg, int dend, int bufD)
{
    const int tid = threadIdx.x;
    const int wg  = tid % 48;         // w-group (4 px)
    const int dd  = tid / 48;         // d within block
    const int w0  = 4 * wg;
    int d = dbeg + 4*(int)blockIdx.x + dd;
    if (d >= dend) d = dend - 1;      // duplicate thread writes identical data
    const int h0 = (int)blockIdx.y * HT1;
    const int c  = (int)blockIdx.z;
    const bool le = (wg == 0), re = (wg == 47);

    const float* __restrict__ Ib = I + (size_t)c*VOL + (size_t)d*HWN + w0;
    const float* __restrict__ Jb = J + (size_t)c*VOL + (size_t)d*HWN + w0;

    // running H-sums: 5 fields x {L = w0-4..w0-1, M = w0..w0+3, R = w0+4..w0+7}
    float4 L0=zero4(),L1=zero4(),L2=zero4(),L3=zero4(),L4=zero4();
    float4 M0=zero4(),M1=zero4(),M2=zero4(),M3=zero4(),M4=zero4();
    float4 R0=zero4(),R1=zero4(),R2=zero4(),R3=zero4(),R4=zero4();

    float4 aIL,aIM,aIR,aJL,aJM,aJR;   // prefetched add row (h+4)
    float4 dIL,dIM,dIR,dJL,dJM,dJR;   // drop row (h-4), re-loaded (cache-hot)

    // edge lanes never load OOB side-spans (exec-masked) -> L/R stay exact 0
#define LOADROW(H, OK, IL, IM, IR, JL, JM, JR) do {                          \
    IL = zero4(); IM = zero4(); IR = zero4();                                \
    JL = zero4(); JM = zero4(); JR = zero4();                                \
    if (OK) {                                                                \
        const float* ri = Ib + (size_t)(H)*WDIM;                             \
        const float* rj = Jb + (size_t)(H)*WDIM;                             \
        IM = *(const float4*)ri; JM = *(const float4*)rj;                    \
        if (!le) { IL = *(const float4*)(ri-4); JL = *(const float4*)(rj-4); } \
        if (!re) { IR = *(const float4*)(ri+4); JR = *(const float4*)(rj+4); } \
    } } while (0)

    // warm-up: accumulate rows h0-4 .. h0+3 (zero padded below h=0)
    for (int k = 0; k < 8; ++k) {
        const int h = h0 - RAD + k;
        LOADROW(h, (h >= 0), dIL,dIM,dIR,dJL,dJM,dJR);
        padd(L0,L1,L2,L3,L4, dIL, dJL);
        padd(M0,M1,M2,M3,M4, dIM, dJM);
        padd(R0,R1,R2,R3,R4, dIR, dJR);
    }
    // prefetch step-0 add row (h0+4, always < HDIM)
    LOADROW(h0 + RAD, true, aIL,aIM,aIR,aJL,aJM,aJR);

    const size_t fstride = (size_t)C2*bufD*HWN;
    __half* const ob = buf + ((size_t)c*bufD + (size_t)(d - d0 + RAD))*HWN + w0;

    // 9-tap window over 12 own H-sums: o0 = sum(L)+sum(M)+R.x, then roll
#define WST(F, LL, MM, RR) {                                                 \
    const float o0 = ((LL.x+LL.y)+(LL.z+LL.w))                               \
                   + ((MM.x+MM.y)+(MM.z+MM.w)) + RR.x;                       \
    const float o1 = o0 - LL.x + RR.y;                                       \
    const float o2 = o1 - LL.y + RR.z;                                       \
    const float o3 = o2 - LL.z + RR.w;                                       \
    uint2 u;                                                                 \
    u.x = __builtin_bit_cast(unsigned int, __floats2half2_rn(o0, o1));       \
    u.y = __builtin_bit_cast(unsigned int, __floats2half2_rn(o2, o3));       \
    *reinterpret_cast<uint2*>(ob + (size_t)(F)*fstride + (size_t)h*WDIM) = u; }

    for (int i = 0; i < HT1; ++i) {
        const int h = h0 + i;
        // issue drop-row loads early (latency hides under padd+window)
        LOADROW(h - RAD, (h - RAD >= 0), dIL,dIM,dIR,dJL,dJM,dJR);
        // accumulate prefetched add row h+4
        padd(L0,L1,L2,L3,L4, aIL, aJL);
        padd(M0,M1,M2,M3,M4, aIM, aJM);
        padd(R0,R1,R2,R3,R4, aIR, aJR);
        // prefetch next step's add row (h+5)
        LOADROW(h + RAD + 1, (i + 1 < HT1) && (h + RAD + 1 < HDIM),
                aIL,aIM,aIR,aJL,aJM,aJR);
        // rs now covers rows h-4..h+4 -> emit 9x9 2D sums for row h
        WST(0, L0, M0, R0) WST(1, L1, M1, R1) WST(2, L2, M2, R2)
        WST(3, L3, M3, R3) WST(4, L4, M4, R4)
        // drop row h-4
        psub(L0,L1,L2,L3,L4, dIL, dJL);
        psub(M0,M1,M2,M3,M4, dIM, dJM);
        psub(R0,R1,R2,R3,R4, dIR, dJR);
    }
#undef WST
#undef LOADROW
}

// -------- K2: D-sum (register ring) + cc + block reduce — no LDS, no syncs --------
// grid: (HWN/256, nsub, C2); block: 256 threads
__global__ __launch_bounds__(256)
void k_dsum(const __half* __restrict__ buf, double* __restrict__ gacc,
            int d0, int bufD, int DS)
{
    const int tid = threadIdx.x;
    const int pix = blockIdx.x*256 + tid;     // (h,w) flat, HWN = 168*256 exact
    const int c   = blockIdx.z;
    const int ds0 = d0 + blockIdx.y*DS;

    const size_t fstride = (size_t)C2*bufD*HWN;
    const __half* base = buf + (size_t)c*bufD*HWN + pix;

    float ring[5][9];
    float rs[5] = {0.f,0.f,0.f,0.f,0.f};
    float acc = 0.f;

    // warm-up: slices ds0-4 .. ds0+3
    #pragma unroll
    for (int k = 0; k < 8; ++k) {
        const int dd = ds0 - RAD + k;
        float v[5] = {0.f,0.f,0.f,0.f,0.f};
        if ((unsigned)dd < (unsigned)DDIM) {
            const __half* pp = base + (size_t)(dd - d0 + RAD)*HWN;
            #pragma unroll
            for (int f = 0; f < 5; ++f) v[f] = __half2float(pp[(size_t)f*fstride]);
        }
        #pragma unroll
        for (int f = 0; f < 5; ++f) { ring[f][k] = v[f]; rs[f] += v[f]; }
    }

    int i = 0;
    while (i < DS) {
        #pragma unroll
        for (int p = 0; p < 9; ++p) {   // i == p (mod 9) whenever body runs
            if (i < DS) {
                const int dd = ds0 + i + RAD;
                float v[5] = {0.f,0.f,0.f,0.f,0.f};
                if (dd < DDIM) {
                    const __half* pp = base + (size_t)(dd - d0 + RAD)*HWN;
                    #pragma unroll
                    for (int f = 0; f < 5; ++f) v[f] = __half2float(pp[(size_t)f*fstride]);
                }
                float S[5];
                #pragma unroll
                for (int f = 0; f < 5; ++f) {
                    rs[f] += v[f];              // full 9x9x9 sum at dd-4
                    S[f] = rs[f];
                    rs[f] -= ring[f][p];        // drop slice dd-8
                    ring[f][(p+8)%9] = v[f];    // keep slice dd
                }
                const float uI    = S[0]*WINV;
                const float uJ    = S[1]*WINV;
                const float cross = S[4] - uJ*S[0];
                const float Iv    = S[2] - uI*S[0];
                const float Jv    = S[3] - uJ*S[1];
                acc += cross*cross / (Iv*Jv + 1e-5f);
                ++i;
            }
        }
    }

    // block reduction -> one double atomic per block
    __shared__ float wred[4];
    #pragma unroll
    for (int off = 32; off > 0; off >>= 1) acc += __shfl_down(acc, off);
    if ((tid & 63) == 0) wred[tid >> 6] = acc;
    __syncthreads();
    if (tid == 0) {
        const float sum = wred[0] + wred[1] + wred[2] + wred[3];
        atomicAdd(gacc, (double)sum);
    }
}

__global__ void k_fin(const double* __restrict__ gacc, float* __restrict__ out)
{
    out[0] = (float)(-gacc[0] / (double)((size_t)C2*DDIM*HDIM*WDIM));
}

extern "C" void kernel_launch(void* const* d_in, const int* in_sizes, int n_in,
                              void* d_out, int out_size, void* d_ws, size_t ws_size,
                              hipStream_t stream)
{
    if (n_in < 2) return;
    const float* I = (const float*)d_in[0];
    const float* J = (const float*)d_in[1];
    float* out = (float*)d_out;
    double* gacc = (double*)d_ws;
    __half* buf = (__half*)((char*)d_ws + 256);

    // choose D-chunk so the 5-field fp16 2D-summed buffer fits ws (192 = 1 chunk)
    static const int cands[] = {192, 96, 48, 24, 12, 6, 4, 2, 1};
    int Dc = 0;
    for (int c : cands) {
        const size_t need = 256 + (size_t)5*C2*(c+8)*HWN*sizeof(__half);
        if (need <= ws_size) { Dc = c; break; }
    }
    if (Dc == 0) return;  // ws too small — cannot run

    hipMemsetAsync(d_ws, 0, 256, stream);   // zero the double accumulator

    const int DS   = (Dc % 48 == 0) ? 48 : Dc;  // K2 sub-chunk along D
    const int nsub = Dc / DS;
    const int bufD = Dc + 8;

    for (int d0 = 0; d0 < DDIM; d0 += Dc) {
        const int dbeg = (d0 - RAD < 0) ? 0 : d0 - RAD;
        const int dend = (d0 + Dc + RAD > DDIM) ? DDIM : d0 + Dc + RAD;
        const int nd   = dend - dbeg;
        dim3 g1((nd + 3)/4, HDIM/HT1, C2);
        k_hwsum<<<g1, dim3(192,1,1), 0, stream>>>(I, J, buf, d0, dbeg, dend, bufD);
        dim3 g2(HWN/256, nsub, C2);
        k_dsum<<<g2, dim3(256,1,1), 0, stream>>>(buf, gacc, d0, bufD, DS);
    }
    k_fin<<<1,1,0,stream>>>(gacc, out);
}